// Round 10
// baseline (453.525 us; speedup 1.0000x reference)
//
#include <hip/hip_runtime.h>
#include <stdint.h>

typedef unsigned short ushort;
typedef __bf16 bf16x8 __attribute__((ext_vector_type(8)));
typedef float f32x4 __attribute__((ext_vector_type(4)));
typedef ushort ushort8 __attribute__((ext_vector_type(8)));
typedef ushort us4 __attribute__((ext_vector_type(4)));

__device__ __forceinline__ float bf2f(ushort u) {
  union { unsigned int i; float f; } v; v.i = ((unsigned int)u) << 16; return v.f;
}
__device__ __forceinline__ ushort f2bf(float f) {
  union { float f; unsigned int i; } v; v.f = f;
  unsigned int r = v.i + 0x7fffu + ((v.i >> 16) & 1u);
  return (ushort)(r >> 16);
}
__device__ __forceinline__ void glds16(const ushort* g, ushort* l) {
  __builtin_amdgcn_global_load_lds(
      (const __attribute__((address_space(1))) void*)g,
      (__attribute__((address_space(3))) void*)l, 16, 0, 0);
}

// counted-vmcnt barrier: retire oldest stages only, keep N in flight (T4)
#define VMB(N)                                                  \
  do {                                                          \
    asm volatile("s_waitcnt vmcnt(" #N ")" ::: "memory");       \
    __builtin_amdgcn_s_barrier();                               \
    __builtin_amdgcn_sched_barrier(0);                          \
  } while (0)

// ---------------- pack: Bt[896][2304] bf16 + bias896 ----------------
__global__ __launch_bounds__(256) void pack_kernel(
    const float* __restrict__ w_kern, const float* __restrict__ b_kern,
    const float* __restrict__ w_badp, const float* __restrict__ b_badp,
    ushort* __restrict__ Bt, float* __restrict__ bias896) {
  int idx = blockIdx.x * 256 + threadIdx.x;
  const int total = 896 * 2304;
  if (idx < total) {
    int o = idx / 2304, k = idx - o * 2304;
    int c = k & 255, pos = k >> 8;
    float v = (o < 864) ? w_kern[(o * 256 + c) * 9 + pos]
                        : w_badp[((o - 864) * 256 + c) * 9 + pos];
    Bt[idx] = f2bf(v);
  } else if (idx < total + 896) {
    int o = idx - total;
    bias896[o] = (o < 864) ? b_kern[o] : b_badp[o - 864];
  }
}

// ---------------- pack2: conv weights -> [tap][oc][ic] bf16 ----------------
__global__ __launch_bounds__(256) void pack2_kernel(
    const float* __restrict__ w1, const float* __restrict__ w2,
    const float* __restrict__ w3, ushort* __restrict__ wp1,
    ushort* __restrict__ wp2, ushort* __restrict__ wp3) {
  int idx = blockIdx.x * 256 + threadIdx.x;
  if (idx < 102400) {                       // wp1 [25][128][32]
    int t = idx >> 12, rm = idx & 4095, o = rm >> 5, c = rm & 31;
    wp1[idx] = f2bf(w1[(o * 32 + c) * 25 + t]);
  } else if (idx < 102400 + 36864) {        // wp2 [9][32][128]
    int j = idx - 102400;
    int t = j >> 12, rm = j & 4095, o = rm >> 7, c = rm & 127;
    wp2[j] = f2bf(w2[(o * 128 + c) * 9 + t]);
  } else if (idx < 102400 + 36864 + 13824) {// wp3 [9][48][32]
    int j = idx - 139264;
    int t = j / 1536, rm = j - t * 1536, o = rm >> 5, c = rm & 31;
    wp3[j] = f2bf(w3[(o * 32 + c) * 9 + t]);
  }
}

// ---------------- feat: per-patch 3x3 VALID conv, 256 ch, relu, bf16 ----------------
__global__ __launch_bounds__(256) void feat_kernel(
    const float* __restrict__ x, const float* __restrict__ w_feat,
    const float* __restrict__ b_feat, ushort* __restrict__ feat) {
  __shared__ float xp[4][3][5][5];
  const int t = threadIdx.x;
  const int n0 = blockIdx.x * 4;
  for (int e = t; e < 300; e += 256) {
    int p = e / 75, rem = e - p * 75;
    int ci = rem / 25, r = rem - ci * 25, i = r / 5, j = r - i * 5;
    int n = n0 + p;
    int b = n / 9216, ph = (n >> 7) % 72, pw = n & 127;
    xp[p][ci][i][j] = x[((b * 3 + ci) * 360 + ph * 5 + i) * 640 + pw * 5 + j];
  }
  float wf[27];
#pragma unroll
  for (int m = 0; m < 27; ++m) wf[m] = w_feat[t * 27 + m];
  const float bv = b_feat[t];
  __syncthreads();
  for (int p = 0; p < 4; ++p) {
    ushort* dst = feat + (size_t)(n0 + p) * 2304 + t;
#pragma unroll
    for (int pi = 0; pi < 3; ++pi)
#pragma unroll
      for (int pj = 0; pj < 3; ++pj) {
        float acc = bv;
#pragma unroll
        for (int ci = 0; ci < 3; ++ci)
#pragma unroll
          for (int ki = 0; ki < 3; ++ki)
#pragma unroll
            for (int kj = 0; kj < 3; ++kj)
              acc = fmaf(xp[p][ci][pi + ki][pj + kj], wf[ci * 9 + ki * 3 + kj], acc);
        dst[(pi * 3 + pj) * 256] = f2bf(fmaxf(acc, 0.f));
      }
  }
}

// ---------------- kern+badp GEMM: MFMA bf16, 128x128, BK=32 ----------------
__global__ __launch_bounds__(256) void gemm_kernel(
    const ushort* __restrict__ A, const ushort* __restrict__ Bt,
    const float* __restrict__ bias, ushort* __restrict__ C) {
  const int K = 2304, N = 896;
  __shared__ __align__(16) ushort lA[3][4096];
  __shared__ __align__(16) ushort lB[3][4096];
  const int bid = blockIdx.x;                 // 1008 = 8 XCD * 18 m * 7 n
  const int xcd = bid & 7, j = bid >> 3;
  const int mblk = xcd * 18 + j / 7, nblk = j % 7;
  const int m0 = mblk * 128, n0 = nblk * 128;
  const int t = threadIdx.x;
  const int lane = t & 63, wave = t >> 6;
  const int wm = wave >> 1, wn = wave & 1;
  const int lp = lane & 15, lk = lane >> 4;
  f32x4 acc[4][4] = {};
  const int srow = t >> 2;
  const int sslot = (t & 3) ^ ((srow >> 1) & 3);
  const ushort* gA = A + (size_t)(m0 + srow) * K + sslot * 8;
  const ushort* gB = Bt + (size_t)(n0 + srow) * K + sslot * 8;
  const int swz = lk ^ ((lp >> 1) & 3);
  const int aoff = (wm * 64 + lp) * 32 + swz * 8;
  const int boff = (wn * 64 + lp) * 32 + swz * 8;

#define KT(x) ((x) < 2304 ? (x) : 2272)
#define GSTAGE(buf, kt)                                       \
  do {                                                        \
    glds16(gA + (kt), &lA[buf][wave * 512]);                  \
    glds16(gA + 64 * K + (kt), &lA[buf][2048 + wave * 512]);  \
    glds16(gB + (kt), &lB[buf][wave * 512]);                  \
    glds16(gB + 64 * K + (kt), &lB[buf][2048 + wave * 512]);  \
  } while (0)

#define GCOMP(buf)                                                            \
  do {                                                                        \
    bf16x8 af[4], bfr[4];                                                     \
    _Pragma("unroll") for (int mi = 0; mi < 4; ++mi)                          \
        af[mi] = __builtin_bit_cast(bf16x8,                                   \
            *(const ushort8*)(&lA[buf][aoff + mi * 512]));                    \
    _Pragma("unroll") for (int ni = 0; ni < 4; ++ni)                          \
        bfr[ni] = __builtin_bit_cast(bf16x8,                                  \
            *(const ushort8*)(&lB[buf][boff + ni * 512]));                    \
    _Pragma("unroll") for (int mi = 0; mi < 4; ++mi)                          \
        _Pragma("unroll") for (int ni = 0; ni < 4; ++ni)                      \
            acc[mi][ni] = __builtin_amdgcn_mfma_f32_16x16x32_bf16(            \
                af[mi], bfr[ni], acc[mi][ni], 0, 0, 0);                       \
  } while (0)

  GSTAGE(0, 0);
  GSTAGE(1, 32);
#pragma unroll 1
  for (int i = 0; i < 72; i += 3) {
    VMB(4); GSTAGE(2, KT((i + 2) * 32)); GCOMP(0);
    VMB(4); GSTAGE(0, KT((i + 3) * 32)); GCOMP(1);
    VMB(4); GSTAGE(1, KT((i + 4) * 32)); GCOMP(2);
  }
#undef GSTAGE
#undef GCOMP
#undef KT

#pragma unroll
  for (int ni = 0; ni < 4; ++ni) {
    int col = n0 + wn * 64 + ni * 16 + lp;
    float bv = bias[col];
#pragma unroll
    for (int mi = 0; mi < 4; ++mi) {
      int row0 = m0 + wm * 64 + mi * 16 + lk * 4;
#pragma unroll
      for (int r = 0; r < 4; ++r)
        C[(size_t)(row0 + r) * N + col] = f2bf(acc[mi][ni][r] + bv);
    }
  }
}

// ---------------- apply: einsum + bias, relu, batch_to_space -> sp NHWC ----------------
// kernbias staged coalesced through LDS (was a stride-54B gather per thread)
__global__ __launch_bounds__(256) void apply_kernel(
    const float* __restrict__ x, const ushort* __restrict__ kernbias,
    ushort* __restrict__ sp) {
  __shared__ float xp[8][3][7][7];
  __shared__ ushort outl[8][32][25];
  __shared__ ushort klds[8 * 896];
  const int t = threadIdx.x;
  const int n0 = blockIdx.x * 8;
  const int b = n0 / 9216, ph = (n0 >> 7) % 72, pw0 = n0 & 127;
  for (int e = t; e < 8 * 3 * 49; e += 256) ((float*)xp)[e] = 0.f;
  for (int e = t; e < 7168; e += 256) klds[e] = kernbias[(size_t)n0 * 896 + e];
  __syncthreads();
  for (int e = t; e < 600; e += 256) {
    int p = e / 75, rem = e - p * 75;
    int ci = rem / 25, r = rem - ci * 25, i = r / 5, j = r - i * 5;
    xp[p][ci][i + 1][j + 1] = x[((b * 3 + ci) * 360 + ph * 5 + i) * 640 + (pw0 + p) * 5 + j];
  }
  __syncthreads();
  const int p = t >> 5, f = t & 31;
  float kk[27];
#pragma unroll
  for (int k = 0; k < 27; ++k) kk[k] = bf2f(klds[p * 896 + f * 27 + k]);
  const float bv = bf2f(klds[p * 896 + 864 + f]);
  for (int l = 0; l < 25; ++l) {
    int li = l / 5, lj = l - li * 5;
    float s = bv;
#pragma unroll
    for (int k = 0; k < 27; ++k) {
      int ci = k / 9, rm = k - ci * 9, ki = rm / 3, kj = rm - ki * 3;
      s = fmaf(xp[p][ci][li + ki][lj + kj], kk[k], s);
    }
    outl[p][f][l] = f2bf(fmaxf(s, 0.f));
  }
  __syncthreads();
  for (int e = t; e < 6400; e += 256) {
    int f2 = e & 31;
    int idx = e >> 5;
    int i = idx / 40, c40 = idx - i * 40;
    int pp = c40 / 5, j = c40 - pp * 5;
    sp[(((size_t)b * 360 + ph * 5 + i) * 640 + pw0 * 5 + c40) * 32 + f2] = outl[pp][f2][i * 5 + j];
  }
}

// ---------------- conv1: 5x5, 32->128, MFMA implicit GEMM, NHWC ----------------
__global__ __launch_bounds__(512, 4) void conv1_kernel(
    const ushort* __restrict__ sp, const ushort* __restrict__ wp1,
    const float* __restrict__ b1, ushort* __restrict__ h1) {
  __shared__ ushort8 lin[8 * 4 * 69];     // 35.3 KB
  __shared__ ushort8 wbuf[4][512];        // 4 x 8 KB
  const int t = threadIdx.x;
  const int lane = t & 63, wave = t >> 6;
  const int wh = wave >> 1, wn = wave & 1;
  const int lp = lane & 15, lk = lane >> 4;
  const int w0 = blockIdx.x * 64, h0 = blockIdx.y * 4, b = blockIdx.z;
  const int srcoff = (t >> 2) * 32 + (((t & 3) ^ ((t >> 3) & 3)) * 8);
#define WSTAGE(bf, tap) glds16(wp1 + (tap) * 4096 + srcoff, (ushort*)&wbuf[bf][wave * 64])
  WSTAGE(0, 0);
  WSTAGE(1, 1);
  WSTAGE(2, 2);
  for (int u = t; u < 8 * 4 * 68; u += 512) {
    int c8 = u & 3, rest = u >> 2;
    int wx = rest % 68, r = rest / 68;
    int gh = h0 - 2 + r, gw = w0 - 2 + wx;
    ushort8 v = {};
    if ((unsigned)gh < 360u && (unsigned)gw < 640u)
      v = *(const ushort8*)(sp + (((size_t)b * 360 + gh) * 640 + gw) * 32 + c8 * 8);
    lin[(r * 4 + c8) * 69 + wx] = v;
  }
  __syncthreads();   // prologue drain

  f32x4 acc[4][4] = {};
  const int wswz = lk ^ ((lp >> 1) & 3);
#pragma unroll
  for (int tp = 0; tp < 25; ++tp) {
    VMB(2);
    {
      const int tn = (tp + 3 < 25) ? tp + 3 : 24;
      WSTAGE((tp + 3) & 3, tn);
    }
    const int ki = tp / 5, kj = tp % 5;
    const ushort8* wb8 = wbuf[tp & 3];
    bf16x8 W[4], Af[4];
#pragma unroll
    for (int nf = 0; nf < 4; ++nf)
      W[nf] = __builtin_bit_cast(bf16x8, wb8[(wn * 64 + nf * 16 + lp) * 4 + wswz]);
    const int ab = (wh + ki) * 276 + lk * 69 + lp + kj;
#pragma unroll
    for (int mf = 0; mf < 4; ++mf)
      Af[mf] = __builtin_bit_cast(bf16x8, lin[ab + mf * 16]);
#pragma unroll
    for (int mf = 0; mf < 4; ++mf)
#pragma unroll
      for (int nf = 0; nf < 4; ++nf)
        acc[mf][nf] = __builtin_amdgcn_mfma_f32_16x16x32_bf16(W[nf], Af[mf], acc[mf][nf], 0, 0, 0);
  }
#undef WSTAGE

  const int h = h0 + wh;
#pragma unroll
  for (int nf = 0; nf < 4; ++nf) {
    const int oc0 = wn * 64 + nf * 16 + lk * 4;
    f32x4 bv = *(const f32x4*)(b1 + oc0);
#pragma unroll
    for (int mf = 0; mf < 4; ++mf) {
      const int w = w0 + mf * 16 + lp;
      us4 pk;
#pragma unroll
      for (int r = 0; r < 4; ++r) pk[r] = f2bf(fmaxf(acc[mf][nf][r] + bv[r], 0.f));
      *(us4*)(&h1[(((size_t)b * 360 + h) * 640 + w) * 128 + oc0]) = pk;
    }
  }
}

// ---------------- conv2: 3x3, 128->32, LDS dbuf, distance-2 reg staging ----------------
__device__ __forceinline__ void c2_load(ushort8* stg, const ushort* __restrict__ h1,
                                        int t, int b, int h0, int w0, int cb) {
#pragma unroll
  for (int j = 0; j < 7; ++j) {
    int u = t + j * 256;
    ushort8 v = {};
    if (u < 1584) {
      int r = u / 264, rem = u - r * 264;
      int c8 = rem / 66, wx = rem - c8 * 66;
      int gh = h0 - 1 + r, gw = w0 - 1 + wx;
      if ((unsigned)gh < 360u && (unsigned)gw < 640u)
        v = *(const ushort8*)(h1 + (((size_t)b * 360 + gh) * 640 + gw) * 128 + cb * 32 + c8 * 8);
    }
    stg[j] = v;
  }
}
__device__ __forceinline__ void c2_write(const ushort8* stg, ushort8* buf, int t) {
#pragma unroll
  for (int j = 0; j < 7; ++j) {
    int u = t + j * 256;
    if (u < 1584) {
      int r = u / 264, rem = u - r * 264;
      int c8 = rem / 66, wx = rem - c8 * 66;
      buf[c8 * 414 + r * 69 + wx] = stg[j];
    }
  }
}
__device__ __forceinline__ void c2_compute(const ushort8* buf, const ushort* __restrict__ wp2,
                                           int cb, int wave, int lp, int lk, f32x4 acc[4][2]) {
#pragma unroll
  for (int ki = 0; ki < 3; ++ki) {
    const int rb = lk * 414 + (wave + ki) * 69;
#pragma unroll
    for (int kj = 0; kj < 3; ++kj) {
      const int tap = ki * 3 + kj;
      bf16x8 bfr[2];
#pragma unroll
      for (int nf = 0; nf < 2; ++nf) {
        ushort8 tmp = *(const ushort8*)(wp2 + tap * 4096 + nf * 2048 + lp * 128 + cb * 32 + lk * 8);
        bfr[nf] = __builtin_bit_cast(bf16x8, tmp);
      }
      bf16x8 afr[4];
#pragma unroll
      for (int mf = 0; mf < 4; ++mf)
        afr[mf] = __builtin_bit_cast(bf16x8, buf[rb + lp + mf * 16 + kj]);
#pragma unroll
      for (int mf = 0; mf < 4; ++mf)
#pragma unroll
        for (int nf = 0; nf < 2; ++nf)
          acc[mf][nf] = __builtin_amdgcn_mfma_f32_16x16x32_bf16(bfr[nf], afr[mf], acc[mf][nf], 0, 0, 0);
    }
  }
}

__global__ __launch_bounds__(256) void conv2_kernel(
    const ushort* __restrict__ h1, const ushort* __restrict__ wp2,
    const float* __restrict__ b2, ushort* __restrict__ h2) {
  __shared__ ushort8 lin[2][4 * 414];
  const int t = threadIdx.x;
  const int lane = t & 63, wave = t >> 6;
  const int lp = lane & 15, lk = lane >> 4;
  const int w0 = blockIdx.x * 64, h0 = blockIdx.y * 4, b = blockIdx.z;
  f32x4 acc[4][2] = {};
  ushort8 stgA[7], stgB[7];
  // distance-2 pipeline: stage loads issued 2 chunks before their LDS write
  c2_load(stgA, h1, t, b, h0, w0, 0);
  c2_load(stgB, h1, t, b, h0, w0, 1);
  // phase 0
  c2_write(stgA, lin[0], t);
  c2_load(stgA, h1, t, b, h0, w0, 2);
  __syncthreads();
  // phase 1
  c2_write(stgB, lin[1], t);
  c2_load(stgB, h1, t, b, h0, w0, 3);
  c2_compute(lin[0], wp2, 0, wave, lp, lk, acc);
  __syncthreads();
  // phase 2
  c2_write(stgA, lin[0], t);
  c2_compute(lin[1], wp2, 1, wave, lp, lk, acc);
  __syncthreads();
  // phase 3
  c2_write(stgB, lin[1], t);
  c2_compute(lin[0], wp2, 2, wave, lp, lk, acc);
  __syncthreads();
  // phase 4
  c2_compute(lin[1], wp2, 3, wave, lp, lk, acc);

  const int h = h0 + wave;
#pragma unroll
  for (int nf = 0; nf < 2; ++nf) {
    const int oc0 = nf * 16 + lk * 4;
    f32x4 bv = *(const f32x4*)(b2 + oc0);
#pragma unroll
    for (int mf = 0; mf < 4; ++mf) {
      const int w = w0 + mf * 16 + lp;
      us4 pk;
#pragma unroll
      for (int r = 0; r < 4; ++r) pk[r] = f2bf(fmaxf(acc[mf][nf][r] + bv[r], 0.f));
      *(us4*)(&h2[(((size_t)b * 360 + h) * 640 + w) * 32 + oc0]) = pk;
    }
  }
}

// ---------------- conv3: 3x3, 32->48, MFMA, fp32 out + fused pixel_shuffle ----------------
__global__ __launch_bounds__(256) void conv3_kernel(
    const ushort* __restrict__ h2, const ushort* __restrict__ wp3,
    const float* __restrict__ b3, float* __restrict__ out) {
  __shared__ ushort8 lin[4 * 4 * 67];
  const int t = threadIdx.x;
  const int lane = t & 63, wave = t >> 6;
  const int wh = wave & 1, wm = wave >> 1;
  const int lp = lane & 15, lk = lane >> 4;
  const int w0 = blockIdx.x * 64, h0 = blockIdx.y * 2, b = blockIdx.z;
  for (int u = t; u < 4 * 4 * 66; u += 256) {
    int c8 = u & 3, rest = u >> 2;
    int wx = rest % 66, r = rest / 66;
    int gh = h0 - 1 + r, gw = w0 - 1 + wx;
    ushort8 v = {};
    if (gh >= 0 && gh < 360 && gw >= 0 && gw < 640)
      v = *(const ushort8*)(h2 + (((size_t)b * 360 + gh) * 640 + gw) * 32 + c8 * 8);
    lin[(r * 4 + c8) * 67 + wx] = v;
  }
  __syncthreads();
  f32x4 acc[2][3] = {};
  const int abase = lk * 67 + wm * 32 + lp;
  const ushort* wbase = wp3 + lp * 32 + lk * 8;
#pragma unroll
  for (int ki = 0; ki < 3; ++ki) {
#pragma unroll
    for (int kj = 0; kj < 3; ++kj) {
      const int tap = ki * 3 + kj;
      bf16x8 bfr[3];
#pragma unroll
      for (int nf = 0; nf < 3; ++nf) {
        ushort8 tmp = *(const ushort8*)(wbase + (size_t)tap * 1536 + nf * 512);
        bfr[nf] = __builtin_bit_cast(bf16x8, tmp);
      }
      bf16x8 afr[2];
#pragma unroll
      for (int mf = 0; mf < 2; ++mf)
        afr[mf] = __builtin_bit_cast(bf16x8, lin[(wh + ki) * 268 + abase + mf * 16 + kj]);
#pragma unroll
      for (int mf = 0; mf < 2; ++mf)
#pragma unroll
        for (int nf = 0; nf < 3; ++nf)
          acc[mf][nf] = __builtin_amdgcn_mfma_f32_16x16x32_bf16(bfr[nf], afr[mf], acc[mf][nf], 0, 0, 0);
    }
  }
  const int h = h0 + wh;
#pragma unroll
  for (int nf = 0; nf < 3; ++nf) {
    f32x4 bv = *(const f32x4*)(b3 + nf * 16 + lk * 4);
#pragma unroll
    for (int mf = 0; mf < 2; ++mf) {
      const int w = w0 + wm * 32 + mf * 16 + lp;
      f32x4 o;
#pragma unroll
      for (int r = 0; r < 4; ++r) o[r] = acc[mf][nf][r] + bv[r];
      *(f32x4*)(&out[(((size_t)b * 3 + nf) * 1440 + h * 4 + lk) * 2560 + (size_t)w * 4]) = o;
    }
  }
}

extern "C" void kernel_launch(void* const* d_in, const int* in_sizes, int n_in,
                              void* d_out, int out_size, void* d_ws, size_t ws_size,
                              hipStream_t stream) {
  const float* x      = (const float*)d_in[0];
  const float* w_feat = (const float*)d_in[1];
  const float* b_feat = (const float*)d_in[2];
  const float* w_kern = (const float*)d_in[3];
  const float* b_kern = (const float*)d_in[4];
  const float* w_badp = (const float*)d_in[5];
  const float* b_badp = (const float*)d_in[6];
  const float* w1 = (const float*)d_in[7];
  const float* b1 = (const float*)d_in[8];
  const float* w2 = (const float*)d_in[9];
  const float* b2 = (const float*)d_in[10];
  const float* w3 = (const float*)d_in[11];
  const float* b3 = (const float*)d_in[12];

  char* ws = (char*)d_ws;
  ushort* feat     = (ushort*)(ws);
  ushort* h1       = (ushort*)(ws);
  ushort* kernbias = (ushort*)(ws + 117964800);
  ushort* h2       = (ushort*)(ws + 117964800);
  ushort* wp1      = (ushort*)(ws + 147456000);
  ushort* wp2      = (ushort*)(ws + 147660800);
  ushort* wp3      = (ushort*)(ws + 147734528);
  ushort* sp       = (ushort*)(ws + 150994944);
  ushort* Bt       = (ushort*)(ws + 180486144);
  float*  bias896  = (float*)(ws + 184614912);

  pack_kernel<<<(896 * 2304 + 896 + 255) / 256, 256, 0, stream>>>(
      w_kern, b_kern, w_badp, b_badp, Bt, bias896);
  feat_kernel<<<4608, 256, 0, stream>>>(x, w_feat, b_feat, feat);
  gemm_kernel<<<1008, 256, 0, stream>>>(feat, Bt, bias896, kernbias);
  apply_kernel<<<2304, 256, 0, stream>>>(x, kernbias, sp);
  pack2_kernel<<<598, 256, 0, stream>>>(w1, w2, w3, wp1, wp2, wp3);
  conv1_kernel<<<dim3(10, 90, 2), 512, 0, stream>>>(sp, wp1, b1, h1);
  conv2_kernel<<<dim3(10, 90, 2), 256, 0, stream>>>(h1, wp2, b2, h2);
  conv3_kernel<<<dim3(10, 180, 2), 256, 0, stream>>>(h2, wp3, b3, (float*)d_out);
}

// Round 11
// 442.944 us; speedup vs baseline: 1.0239x; 1.0239x over previous
//
#include <hip/hip_runtime.h>
#include <stdint.h>

typedef unsigned short ushort;
typedef __bf16 bf16x8 __attribute__((ext_vector_type(8)));
typedef float f32x4 __attribute__((ext_vector_type(4)));
typedef ushort ushort8 __attribute__((ext_vector_type(8)));
typedef ushort us4 __attribute__((ext_vector_type(4)));

__device__ __forceinline__ float bf2f(ushort u) {
  union { unsigned int i; float f; } v; v.i = ((unsigned int)u) << 16; return v.f;
}
__device__ __forceinline__ ushort f2bf(float f) {
  union { float f; unsigned int i; } v; v.f = f;
  unsigned int r = v.i + 0x7fffu + ((v.i >> 16) & 1u);
  return (ushort)(r >> 16);
}
__device__ __forceinline__ void glds16(const ushort* g, ushort* l) {
  __builtin_amdgcn_global_load_lds(
      (const __attribute__((address_space(1))) void*)g,
      (__attribute__((address_space(3))) void*)l, 16, 0, 0);
}

// counted-vmcnt barrier: retire oldest stages only, keep N in flight (T4)
#define VMB(N)                                                  \
  do {                                                          \
    asm volatile("s_waitcnt vmcnt(" #N ")" ::: "memory");       \
    __builtin_amdgcn_s_barrier();                               \
    __builtin_amdgcn_sched_barrier(0);                          \
  } while (0)

// ---------------- pack: Bt[896][2304] bf16 + bias896 ----------------
__global__ __launch_bounds__(256) void pack_kernel(
    const float* __restrict__ w_kern, const float* __restrict__ b_kern,
    const float* __restrict__ w_badp, const float* __restrict__ b_badp,
    ushort* __restrict__ Bt, float* __restrict__ bias896) {
  int idx = blockIdx.x * 256 + threadIdx.x;
  const int total = 896 * 2304;
  if (idx < total) {
    int o = idx / 2304, k = idx - o * 2304;
    int c = k & 255, pos = k >> 8;
    float v = (o < 864) ? w_kern[(o * 256 + c) * 9 + pos]
                        : w_badp[((o - 864) * 256 + c) * 9 + pos];
    Bt[idx] = f2bf(v);
  } else if (idx < total + 896) {
    int o = idx - total;
    bias896[o] = (o < 864) ? b_kern[o] : b_badp[o - 864];
  }
}

// ---------------- pack2: conv weights -> [tap][oc][ic] bf16 ----------------
__global__ __launch_bounds__(256) void pack2_kernel(
    const float* __restrict__ w1, const float* __restrict__ w2,
    const float* __restrict__ w3, ushort* __restrict__ wp1,
    ushort* __restrict__ wp2, ushort* __restrict__ wp3) {
  int idx = blockIdx.x * 256 + threadIdx.x;
  if (idx < 102400) {                       // wp1 [25][128][32]
    int t = idx >> 12, rm = idx & 4095, o = rm >> 5, c = rm & 31;
    wp1[idx] = f2bf(w1[(o * 32 + c) * 25 + t]);
  } else if (idx < 102400 + 36864) {        // wp2 [9][32][128]
    int j = idx - 102400;
    int t = j >> 12, rm = j & 4095, o = rm >> 7, c = rm & 127;
    wp2[j] = f2bf(w2[(o * 128 + c) * 9 + t]);
  } else if (idx < 102400 + 36864 + 13824) {// wp3 [9][48][32]
    int j = idx - 139264;
    int t = j / 1536, rm = j - t * 1536, o = rm >> 5, c = rm & 31;
    wp3[j] = f2bf(w3[(o * 32 + c) * 9 + t]);
  }
}

// ---------------- feat: per-patch 3x3 VALID conv, 256 ch, relu, bf16 ----------------
__global__ __launch_bounds__(256) void feat_kernel(
    const float* __restrict__ x, const float* __restrict__ w_feat,
    const float* __restrict__ b_feat, ushort* __restrict__ feat) {
  __shared__ float xp[4][3][5][5];
  const int t = threadIdx.x;
  const int n0 = blockIdx.x * 4;
  for (int e = t; e < 300; e += 256) {
    int p = e / 75, rem = e - p * 75;
    int ci = rem / 25, r = rem - ci * 25, i = r / 5, j = r - i * 5;
    int n = n0 + p;
    int b = n / 9216, ph = (n >> 7) % 72, pw = n & 127;
    xp[p][ci][i][j] = x[((b * 3 + ci) * 360 + ph * 5 + i) * 640 + pw * 5 + j];
  }
  float wf[27];
#pragma unroll
  for (int m = 0; m < 27; ++m) wf[m] = w_feat[t * 27 + m];
  const float bv = b_feat[t];
  __syncthreads();
  for (int p = 0; p < 4; ++p) {
    ushort* dst = feat + (size_t)(n0 + p) * 2304 + t;
#pragma unroll
    for (int pi = 0; pi < 3; ++pi)
#pragma unroll
      for (int pj = 0; pj < 3; ++pj) {
        float acc = bv;
#pragma unroll
        for (int ci = 0; ci < 3; ++ci)
#pragma unroll
          for (int ki = 0; ki < 3; ++ki)
#pragma unroll
            for (int kj = 0; kj < 3; ++kj)
              acc = fmaf(xp[p][ci][pi + ki][pj + kj], wf[ci * 9 + ki * 3 + kj], acc);
        dst[(pi * 3 + pj) * 256] = f2bf(fmaxf(acc, 0.f));
      }
  }
}

// ---------------- kern+badp GEMM: MFMA bf16, 128x128, BK=32 ----------------
__global__ __launch_bounds__(256) void gemm_kernel(
    const ushort* __restrict__ A, const ushort* __restrict__ Bt,
    const float* __restrict__ bias, ushort* __restrict__ C) {
  const int K = 2304, N = 896;
  __shared__ __align__(16) ushort lA[3][4096];
  __shared__ __align__(16) ushort lB[3][4096];
  const int bid = blockIdx.x;                 // 1008 = 8 XCD * 18 m * 7 n
  const int xcd = bid & 7, j = bid >> 3;
  const int mblk = xcd * 18 + j / 7, nblk = j % 7;
  const int m0 = mblk * 128, n0 = nblk * 128;
  const int t = threadIdx.x;
  const int lane = t & 63, wave = t >> 6;
  const int wm = wave >> 1, wn = wave & 1;
  const int lp = lane & 15, lk = lane >> 4;
  f32x4 acc[4][4] = {};
  const int srow = t >> 2;
  const int sslot = (t & 3) ^ ((srow >> 1) & 3);
  const ushort* gA = A + (size_t)(m0 + srow) * K + sslot * 8;
  const ushort* gB = Bt + (size_t)(n0 + srow) * K + sslot * 8;
  const int swz = lk ^ ((lp >> 1) & 3);
  const int aoff = (wm * 64 + lp) * 32 + swz * 8;
  const int boff = (wn * 64 + lp) * 32 + swz * 8;

#define KT(x) ((x) < 2304 ? (x) : 2272)
#define GSTAGE(buf, kt)                                       \
  do {                                                        \
    glds16(gA + (kt), &lA[buf][wave * 512]);                  \
    glds16(gA + 64 * K + (kt), &lA[buf][2048 + wave * 512]);  \
    glds16(gB + (kt), &lB[buf][wave * 512]);                  \
    glds16(gB + 64 * K + (kt), &lB[buf][2048 + wave * 512]);  \
  } while (0)

#define GCOMP(buf)                                                            \
  do {                                                                        \
    bf16x8 af[4], bfr[4];                                                     \
    _Pragma("unroll") for (int mi = 0; mi < 4; ++mi)                          \
        af[mi] = __builtin_bit_cast(bf16x8,                                   \
            *(const ushort8*)(&lA[buf][aoff + mi * 512]));                    \
    _Pragma("unroll") for (int ni = 0; ni < 4; ++ni)                          \
        bfr[ni] = __builtin_bit_cast(bf16x8,                                  \
            *(const ushort8*)(&lB[buf][boff + ni * 512]));                    \
    _Pragma("unroll") for (int mi = 0; mi < 4; ++mi)                          \
        _Pragma("unroll") for (int ni = 0; ni < 4; ++ni)                      \
            acc[mi][ni] = __builtin_amdgcn_mfma_f32_16x16x32_bf16(            \
                af[mi], bfr[ni], acc[mi][ni], 0, 0, 0);                       \
  } while (0)

  GSTAGE(0, 0);
  GSTAGE(1, 32);
#pragma unroll 1
  for (int i = 0; i < 72; i += 3) {
    VMB(4); GSTAGE(2, KT((i + 2) * 32)); GCOMP(0);
    VMB(4); GSTAGE(0, KT((i + 3) * 32)); GCOMP(1);
    VMB(4); GSTAGE(1, KT((i + 4) * 32)); GCOMP(2);
  }
#undef GSTAGE
#undef GCOMP
#undef KT

#pragma unroll
  for (int ni = 0; ni < 4; ++ni) {
    int col = n0 + wn * 64 + ni * 16 + lp;
    float bv = bias[col];
#pragma unroll
    for (int mi = 0; mi < 4; ++mi) {
      int row0 = m0 + wm * 64 + mi * 16 + lk * 4;
#pragma unroll
      for (int r = 0; r < 4; ++r)
        C[(size_t)(row0 + r) * N + col] = f2bf(acc[mi][ni][r] + bv);
    }
  }
}

// ---------------- apply: einsum + bias, relu, batch_to_space -> sp NHWC ----------------
__global__ __launch_bounds__(256) void apply_kernel(
    const float* __restrict__ x, const ushort* __restrict__ kernbias,
    ushort* __restrict__ sp) {
  __shared__ float xp[8][3][7][7];
  __shared__ ushort outl[8][32][25];
  __shared__ ushort klds[8 * 896];
  const int t = threadIdx.x;
  const int n0 = blockIdx.x * 8;
  const int b = n0 / 9216, ph = (n0 >> 7) % 72, pw0 = n0 & 127;
  for (int e = t; e < 8 * 3 * 49; e += 256) ((float*)xp)[e] = 0.f;
  for (int e = t; e < 7168; e += 256) klds[e] = kernbias[(size_t)n0 * 896 + e];
  __syncthreads();
  for (int e = t; e < 600; e += 256) {
    int p = e / 75, rem = e - p * 75;
    int ci = rem / 25, r = rem - ci * 25, i = r / 5, j = r - i * 5;
    xp[p][ci][i + 1][j + 1] = x[((b * 3 + ci) * 360 + ph * 5 + i) * 640 + (pw0 + p) * 5 + j];
  }
  __syncthreads();
  const int p = t >> 5, f = t & 31;
  float kk[27];
#pragma unroll
  for (int k = 0; k < 27; ++k) kk[k] = bf2f(klds[p * 896 + f * 27 + k]);
  const float bv = bf2f(klds[p * 896 + 864 + f]);
  for (int l = 0; l < 25; ++l) {
    int li = l / 5, lj = l - li * 5;
    float s = bv;
#pragma unroll
    for (int k = 0; k < 27; ++k) {
      int ci = k / 9, rm = k - ci * 9, ki = rm / 3, kj = rm - ki * 3;
      s = fmaf(xp[p][ci][li + ki][lj + kj], kk[k], s);
    }
    outl[p][f][l] = f2bf(fmaxf(s, 0.f));
  }
  __syncthreads();
  for (int e = t; e < 6400; e += 256) {
    int f2 = e & 31;
    int idx = e >> 5;
    int i = idx / 40, c40 = idx - i * 40;
    int pp = c40 / 5, j = c40 - pp * 5;
    sp[(((size_t)b * 360 + ph * 5 + i) * 640 + pw0 * 5 + c40) * 32 + f2] = outl[pp][f2][i * 5 + j];
  }
}

// ---------------- conv1: 5x5, 32->128, MFMA implicit GEMM, NHWC ----------------
__global__ __launch_bounds__(512, 4) void conv1_kernel(
    const ushort* __restrict__ sp, const ushort* __restrict__ wp1,
    const float* __restrict__ b1, ushort* __restrict__ h1) {
  __shared__ ushort8 lin[8 * 4 * 69];     // 35.3 KB
  __shared__ ushort8 wbuf[4][512];        // 4 x 8 KB
  const int t = threadIdx.x;
  const int lane = t & 63, wave = t >> 6;
  const int wh = wave >> 1, wn = wave & 1;
  const int lp = lane & 15, lk = lane >> 4;
  const int w0 = blockIdx.x * 64, h0 = blockIdx.y * 4, b = blockIdx.z;
  const int srcoff = (t >> 2) * 32 + (((t & 3) ^ ((t >> 3) & 3)) * 8);
#define WSTAGE(bf, tap) glds16(wp1 + (tap) * 4096 + srcoff, (ushort*)&wbuf[bf][wave * 64])
  WSTAGE(0, 0);
  WSTAGE(1, 1);
  WSTAGE(2, 2);
  for (int u = t; u < 8 * 4 * 68; u += 512) {
    int c8 = u & 3, rest = u >> 2;
    int wx = rest % 68, r = rest / 68;
    int gh = h0 - 2 + r, gw = w0 - 2 + wx;
    ushort8 v = {};
    if ((unsigned)gh < 360u && (unsigned)gw < 640u)
      v = *(const ushort8*)(sp + (((size_t)b * 360 + gh) * 640 + gw) * 32 + c8 * 8);
    lin[(r * 4 + c8) * 69 + wx] = v;
  }
  __syncthreads();   // prologue drain

  f32x4 acc[4][4] = {};
  const int wswz = lk ^ ((lp >> 1) & 3);
#pragma unroll
  for (int tp = 0; tp < 25; ++tp) {
    VMB(2);
    {
      const int tn = (tp + 3 < 25) ? tp + 3 : 24;
      WSTAGE((tp + 3) & 3, tn);
    }
    const int ki = tp / 5, kj = tp % 5;
    const ushort8* wb8 = wbuf[tp & 3];
    bf16x8 W[4], Af[4];
#pragma unroll
    for (int nf = 0; nf < 4; ++nf)
      W[nf] = __builtin_bit_cast(bf16x8, wb8[(wn * 64 + nf * 16 + lp) * 4 + wswz]);
    const int ab = (wh + ki) * 276 + lk * 69 + lp + kj;
#pragma unroll
    for (int mf = 0; mf < 4; ++mf)
      Af[mf] = __builtin_bit_cast(bf16x8, lin[ab + mf * 16]);
#pragma unroll
    for (int mf = 0; mf < 4; ++mf)
#pragma unroll
      for (int nf = 0; nf < 4; ++nf)
        acc[mf][nf] = __builtin_amdgcn_mfma_f32_16x16x32_bf16(W[nf], Af[mf], acc[mf][nf], 0, 0, 0);
  }
#undef WSTAGE

  const int h = h0 + wh;
#pragma unroll
  for (int nf = 0; nf < 4; ++nf) {
    const int oc0 = wn * 64 + nf * 16 + lk * 4;
    f32x4 bv = *(const f32x4*)(b1 + oc0);
#pragma unroll
    for (int mf = 0; mf < 4; ++mf) {
      const int w = w0 + mf * 16 + lp;
      us4 pk;
#pragma unroll
      for (int r = 0; r < 4; ++r) pk[r] = f2bf(fmaxf(acc[mf][nf][r] + bv[r], 0.f));
      *(us4*)(&h1[(((size_t)b * 360 + h) * 640 + w) * 128 + oc0]) = pk;
    }
  }
}

// ---------------- conv2: 3x3, 128->32, LDS dbuf, coalesced c8-fastest staging ----------------
// u -> (c8 fastest, wx, r): 4 consecutive threads read one pixel's 64 contiguous
// bytes (was wx-fastest = 16B/lane at stride 256B = 4-8x request amplification).
__device__ __forceinline__ void c2_load(ushort8* stg, const ushort* __restrict__ h1,
                                        int t, int b, int h0, int w0, int cb) {
#pragma unroll
  for (int j = 0; j < 7; ++j) {
    int u = t + j * 256;
    ushort8 v = {};
    if (u < 1584) {
      int c8 = u & 3, v2 = u >> 2;
      int r = v2 / 66, wx = v2 - r * 66;
      int gh = h0 - 1 + r, gw = w0 - 1 + wx;
      if ((unsigned)gh < 360u && (unsigned)gw < 640u)
        v = *(const ushort8*)(h1 + (((size_t)b * 360 + gh) * 640 + gw) * 128 + cb * 32 + c8 * 8);
    }
    stg[j] = v;
  }
}
__device__ __forceinline__ void c2_write(const ushort8* stg, ushort8* buf, int t) {
#pragma unroll
  for (int j = 0; j < 7; ++j) {
    int u = t + j * 256;
    if (u < 1584) {
      int c8 = u & 3, v2 = u >> 2;
      int r = v2 / 66, wx = v2 - r * 66;
      buf[c8 * 414 + r * 69 + wx] = stg[j];
    }
  }
}
__device__ __forceinline__ void c2_compute(const ushort8* buf, const ushort* __restrict__ wp2,
                                           int cb, int wave, int lp, int lk, f32x4 acc[4][2]) {
#pragma unroll
  for (int ki = 0; ki < 3; ++ki) {
    const int rb = lk * 414 + (wave + ki) * 69;
#pragma unroll
    for (int kj = 0; kj < 3; ++kj) {
      const int tap = ki * 3 + kj;
      bf16x8 bfr[2];
#pragma unroll
      for (int nf = 0; nf < 2; ++nf) {
        ushort8 tmp = *(const ushort8*)(wp2 + tap * 4096 + nf * 2048 + lp * 128 + cb * 32 + lk * 8);
        bfr[nf] = __builtin_bit_cast(bf16x8, tmp);
      }
      bf16x8 afr[4];
#pragma unroll
      for (int mf = 0; mf < 4; ++mf)
        afr[mf] = __builtin_bit_cast(bf16x8, buf[rb + lp + mf * 16 + kj]);
#pragma unroll
      for (int mf = 0; mf < 4; ++mf)
#pragma unroll
        for (int nf = 0; nf < 2; ++nf)
          acc[mf][nf] = __builtin_amdgcn_mfma_f32_16x16x32_bf16(bfr[nf], afr[mf], acc[mf][nf], 0, 0, 0);
    }
  }
}

__global__ __launch_bounds__(256) void conv2_kernel(
    const ushort* __restrict__ h1, const ushort* __restrict__ wp2,
    const float* __restrict__ b2, ushort* __restrict__ h2) {
  __shared__ ushort8 lin[2][4 * 414];
  const int t = threadIdx.x;
  const int lane = t & 63, wave = t >> 6;
  const int lp = lane & 15, lk = lane >> 4;
  const int w0 = blockIdx.x * 64, h0 = blockIdx.y * 4, b = blockIdx.z;
  f32x4 acc[4][2] = {};
  ushort8 stgA[7], stgB[7];
  c2_load(stgA, h1, t, b, h0, w0, 0);
  c2_load(stgB, h1, t, b, h0, w0, 1);
  // phase 0
  c2_write(stgA, lin[0], t);
  c2_load(stgA, h1, t, b, h0, w0, 2);
  __syncthreads();
  // phase 1
  c2_write(stgB, lin[1], t);
  c2_load(stgB, h1, t, b, h0, w0, 3);
  c2_compute(lin[0], wp2, 0, wave, lp, lk, acc);
  __syncthreads();
  // phase 2
  c2_write(stgA, lin[0], t);
  c2_compute(lin[1], wp2, 1, wave, lp, lk, acc);
  __syncthreads();
  // phase 3
  c2_write(stgB, lin[1], t);
  c2_compute(lin[0], wp2, 2, wave, lp, lk, acc);
  __syncthreads();
  // phase 4
  c2_compute(lin[1], wp2, 3, wave, lp, lk, acc);

  const int h = h0 + wave;
#pragma unroll
  for (int nf = 0; nf < 2; ++nf) {
    const int oc0 = nf * 16 + lk * 4;
    f32x4 bv = *(const f32x4*)(b2 + oc0);
#pragma unroll
    for (int mf = 0; mf < 4; ++mf) {
      const int w = w0 + mf * 16 + lp;
      us4 pk;
#pragma unroll
      for (int r = 0; r < 4; ++r) pk[r] = f2bf(fmaxf(acc[mf][nf][r] + bv[r], 0.f));
      *(us4*)(&h2[(((size_t)b * 360 + h) * 640 + w) * 32 + oc0]) = pk;
    }
  }
}

// ---------------- conv3: 3x3, 32->48, MFMA, fp32 out + fused pixel_shuffle ----------------
__global__ __launch_bounds__(256) void conv3_kernel(
    const ushort* __restrict__ h2, const ushort* __restrict__ wp3,
    const float* __restrict__ b3, float* __restrict__ out) {
  __shared__ ushort8 lin[4 * 4 * 67];
  const int t = threadIdx.x;
  const int lane = t & 63, wave = t >> 6;
  const int wh = wave & 1, wm = wave >> 1;
  const int lp = lane & 15, lk = lane >> 4;
  const int w0 = blockIdx.x * 64, h0 = blockIdx.y * 2, b = blockIdx.z;
  for (int u = t; u < 4 * 4 * 66; u += 256) {
    int c8 = u & 3, rest = u >> 2;
    int wx = rest % 66, r = rest / 66;
    int gh = h0 - 1 + r, gw = w0 - 1 + wx;
    ushort8 v = {};
    if (gh >= 0 && gh < 360 && gw >= 0 && gw < 640)
      v = *(const ushort8*)(h2 + (((size_t)b * 360 + gh) * 640 + gw) * 32 + c8 * 8);
    lin[(r * 4 + c8) * 67 + wx] = v;
  }
  __syncthreads();
  f32x4 acc[2][3] = {};
  const int abase = lk * 67 + wm * 32 + lp;
  const ushort* wbase = wp3 + lp * 32 + lk * 8;
#pragma unroll
  for (int ki = 0; ki < 3; ++ki) {
#pragma unroll
    for (int kj = 0; kj < 3; ++kj) {
      const int tap = ki * 3 + kj;
      bf16x8 bfr[3];
#pragma unroll
      for (int nf = 0; nf < 3; ++nf) {
        ushort8 tmp = *(const ushort8*)(wbase + (size_t)tap * 1536 + nf * 512);
        bfr[nf] = __builtin_bit_cast(bf16x8, tmp);
      }
      bf16x8 afr[2];
#pragma unroll
      for (int mf = 0; mf < 2; ++mf)
        afr[mf] = __builtin_bit_cast(bf16x8, lin[(wh + ki) * 268 + abase + mf * 16 + kj]);
#pragma unroll
      for (int mf = 0; mf < 2; ++mf)
#pragma unroll
        for (int nf = 0; nf < 3; ++nf)
          acc[mf][nf] = __builtin_amdgcn_mfma_f32_16x16x32_bf16(bfr[nf], afr[mf], acc[mf][nf], 0, 0, 0);
    }
  }
  const int h = h0 + wh;
#pragma unroll
  for (int nf = 0; nf < 3; ++nf) {
    f32x4 bv = *(const f32x4*)(b3 + nf * 16 + lk * 4);
#pragma unroll
    for (int mf = 0; mf < 2; ++mf) {
      const int w = w0 + wm * 32 + mf * 16 + lp;
      f32x4 o;
#pragma unroll
      for (int r = 0; r < 4; ++r) o[r] = acc[mf][nf][r] + bv[r];
      *(f32x4*)(&out[(((size_t)b * 3 + nf) * 1440 + h * 4 + lk) * 2560 + (size_t)w * 4]) = o;
    }
  }
}

extern "C" void kernel_launch(void* const* d_in, const int* in_sizes, int n_in,
                              void* d_out, int out_size, void* d_ws, size_t ws_size,
                              hipStream_t stream) {
  const float* x      = (const float*)d_in[0];
  const float* w_feat = (const float*)d_in[1];
  const float* b_feat = (const float*)d_in[2];
  const float* w_kern = (const float*)d_in[3];
  const float* b_kern = (const float*)d_in[4];
  const float* w_badp = (const float*)d_in[5];
  const float* b_badp = (const float*)d_in[6];
  const float* w1 = (const float*)d_in[7];
  const float* b1 = (const float*)d_in[8];
  const float* w2 = (const float*)d_in[9];
  const float* b2 = (const float*)d_in[10];
  const float* w3 = (const float*)d_in[11];
  const float* b3 = (const float*)d_in[12];

  char* ws = (char*)d_ws;
  ushort* feat     = (ushort*)(ws);
  ushort* h1       = (ushort*)(ws);
  ushort* kernbias = (ushort*)(ws + 117964800);
  ushort* h2       = (ushort*)(ws + 117964800);
  ushort* wp1      = (ushort*)(ws + 147456000);
  ushort* wp2      = (ushort*)(ws + 147660800);
  ushort* wp3      = (ushort*)(ws + 147734528);
  ushort* sp       = (ushort*)(ws + 150994944);
  ushort* Bt       = (ushort*)(ws + 180486144);
  float*  bias896  = (float*)(ws + 184614912);

  pack_kernel<<<(896 * 2304 + 896 + 255) / 256, 256, 0, stream>>>(
      w_kern, b_kern, w_badp, b_badp, Bt, bias896);
  feat_kernel<<<4608, 256, 0, stream>>>(x, w_feat, b_feat, feat);
  gemm_kernel<<<1008, 256, 0, stream>>>(feat, Bt, bias896, kernbias);
  apply_kernel<<<2304, 256, 0, stream>>>(x, kernbias, sp);
  pack2_kernel<<<598, 256, 0, stream>>>(w1, w2, w3, wp1, wp2, wp3);
  conv1_kernel<<<dim3(10, 90, 2), 512, 0, stream>>>(sp, wp1, b1, h1);
  conv2_kernel<<<dim3(10, 90, 2), 256, 0, stream>>>(h1, wp2, b2, h2);
  conv3_kernel<<<dim3(10, 180, 2), 256, 0, stream>>>(h2, wp3, b3, (float*)d_out);
}